// Round 1
// baseline (3813.218 us; speedup 1.0000x reference)
//
#include <hip/hip_runtime.h>
#include <hip/hip_bf16.h>

// Problem constants
#define BATCH 512
#define TT 60
#define EDIM 300
#define HDIM 512
#define NG 2048          // 4*H
#define KREAL 812        // E + H
#define KPAD 832         // padded to multiple of 64
#define MDIM 256

typedef __bf16 bf16x4 __attribute__((ext_vector_type(4)));
typedef __bf16 bf16x8 __attribute__((ext_vector_type(8)));
typedef float  f32x16 __attribute__((ext_vector_type(16)));

__device__ __forceinline__ float sigm(float x) {
    return 1.0f / (1.0f + __expf(-x));
}
__device__ __forceinline__ float tanh_fast(float x) {
    float e = __expf(-2.0f * fabsf(x));
    float r = (1.0f - e) / (1.0f + e);
    return x >= 0.0f ? r : -r;
}

// ---------------------------------------------------------------------------
// Weight prep: lstm_kernel [812][2048] fp32  ->  Wt_hi/Wt_lo [2048][832] bf16
// (transposed, k-contiguous, zero-padded k in [812,832))
// grid: 13 (k-tiles) x 32 (n-tiles) = 416 blocks, 256 threads
// ---------------------------------------------------------------------------
__global__ __launch_bounds__(256) void prep_w(const float* __restrict__ kern,
                                              __bf16* __restrict__ wt_hi,
                                              __bf16* __restrict__ wt_lo) {
    __shared__ float tile[64][65];
    int bk = blockIdx.x % 13;   // k-tile
    int bn = blockIdx.x / 13;   // n-tile
    int k0 = bk * 64, n0 = bn * 64;
    int tid = threadIdx.x;
#pragma unroll
    for (int i = 0; i < 16; ++i) {
        int id = i * 256 + tid;          // 0..4095
        int kk = id >> 6, nn = id & 63;
        int kg = k0 + kk;
        tile[kk][nn] = (kg < KREAL) ? kern[(size_t)kg * NG + n0 + nn] : 0.0f;
    }
    __syncthreads();
#pragma unroll
    for (int i = 0; i < 16; ++i) {
        int id = i * 256 + tid;
        int nn = id >> 6, kk = id & 63;
        float v = tile[kk][nn];
        __bf16 h = (__bf16)v;
        __bf16 l = (__bf16)(v - (float)h);
        size_t o = (size_t)(n0 + nn) * KPAD + k0 + kk;
        wt_hi[o] = h;
        wt_lo[o] = l;
    }
}

// ---------------------------------------------------------------------------
// One LSTM time step for BOTH sequences (batch rows 0..511 = seq1, 512..1023 = seq2)
// grid: 256 blocks = 8 batch-tiles (128 rows) x 32 col-groups (16 h-cols)
// block: 256 threads (4 waves); split-bf16 MFMA 32x32x16, K = 832
// ---------------------------------------------------------------------------
#define ASTR 72   // LDS leading-dim stride (elems) for A tiles (144 B, 16B-aligned, odd 16B-units)
#define BSTR 72
#define ZSTR 72   // z scratch stride in f32

__global__ __launch_bounds__(256) void lstm_step(
    int t,
    const int* __restrict__ in1, const int* __restrict__ in2,
    const int* __restrict__ sl1, const int* __restrict__ sl2,
    const float* __restrict__ emb, const float* __restrict__ bias,
    const __bf16* __restrict__ wt_hi, const __bf16* __restrict__ wt_lo,
    float* __restrict__ h_state, float* __restrict__ c_state) {

    // LDS layout: A_hi [128*72] | A_lo [128*72] | B_hi [64*72] | B_lo [64*72]  (bf16)
    // epilogue reuses the A region as z scratch [128][72] f32 (36864 B exactly)
    __shared__ __align__(16) char smem_raw[(128 * ASTR * 2 + 64 * BSTR * 2) * 2];
    __bf16* A_hi = (__bf16*)smem_raw;
    __bf16* A_lo = A_hi + 128 * ASTR;
    __bf16* B_hi = A_lo + 128 * ASTR;
    __bf16* B_lo = B_hi + 64 * BSTR;
    __shared__ int toks[128];

    int tid = threadIdx.x;
    int bx = blockIdx.x;
    int bt = bx >> 5;          // batch tile 0..7
    int cg = bx & 31;          // col-group 0..31
    int row0 = bt * 128;

    if (tid < 128) {
        int rg = row0 + tid;
        int b = rg & 511;
        toks[tid] = ((rg >> 9) ? in2 : in1)[b * TT + t];
    }

    int w = tid >> 6;          // wave id 0..3 -> m-strip rows [32w, 32w+32)
    int lane = tid & 63;
    int l31 = lane & 31;
    int half8 = (lane >> 5) << 3;   // k sub-offset 0 or 8

    f32x16 acc[2];
#pragma unroll
    for (int nt = 0; nt < 2; ++nt)
#pragma unroll
        for (int r = 0; r < 16; ++r) acc[nt][r] = 0.0f;

    for (int kc = 0; kc < 13; ++kc) {
        int k0 = kc * 64;
        __syncthreads();
        // ---- stage A: 128 rows x 64 k, fp32 sources -> hi/lo bf16 ----
#pragma unroll
        for (int i = 0; i < 8; ++i) {
            int cid = i * 256 + tid;        // 0..2047 float4-chunks
            int r = cid >> 4;               // row 0..127
            int c4 = (cid & 15) * 4;        // k offset within chunk
            int kg = k0 + c4;
            float4 v;
            if (kg < EDIM) {
                v = *(const float4*)(emb + (size_t)toks[r] * EDIM + kg);
            } else if (kg < KREAL) {
                v = *(const float4*)(h_state + (size_t)(row0 + r) * HDIM + (kg - EDIM));
            } else {
                v = make_float4(0.f, 0.f, 0.f, 0.f);
            }
            __bf16 h0 = (__bf16)v.x, h1 = (__bf16)v.y, h2 = (__bf16)v.z, h3 = (__bf16)v.w;
            bf16x4 hv = {h0, h1, h2, h3};
            bf16x4 lv = {(__bf16)(v.x - (float)h0), (__bf16)(v.y - (float)h1),
                         (__bf16)(v.z - (float)h2), (__bf16)(v.w - (float)h3)};
            *(bf16x4*)(A_hi + r * ASTR + c4) = hv;
            *(bf16x4*)(A_lo + r * ASTR + c4) = lv;
        }
        // ---- stage B: 64 z-cols (4 gate strips of 16) x 64 k, hi+lo ----
#pragma unroll
        for (int i = 0; i < 4; ++i) {
            int cid = i * 256 + tid;        // 0..1023 chunks of 8 bf16
            int isLo = cid >> 9;
            int id2 = cid & 511;
            int rB = id2 >> 3;              // 0..63
            int c8 = (id2 & 7) * 8;
            int ng = ((rB >> 4) << 9) + (cg << 4) + (rB & 15);  // gate*512 + cg*16 + c
            const __bf16* src = (isLo ? wt_lo : wt_hi) + (size_t)ng * KPAD + k0 + c8;
            __bf16* dst = (isLo ? B_lo : B_hi) + rB * BSTR + c8;
            *(bf16x8*)dst = *(const bf16x8*)src;
        }
        __syncthreads();
        // ---- MFMA: wave w does m-strip w, both n-tiles, 3 split products ----
        const __bf16* Ab = A_hi + (w * 32 + l31) * ASTR + half8;
        const __bf16* Alb = A_lo + (w * 32 + l31) * ASTR + half8;
#pragma unroll
        for (int kk = 0; kk < 64; kk += 16) {
            bf16x8 ah = *(const bf16x8*)(Ab + kk);
            bf16x8 al = *(const bf16x8*)(Alb + kk);
#pragma unroll
            for (int nt = 0; nt < 2; ++nt) {
                const __bf16* Bb = B_hi + (nt * 32 + l31) * BSTR + half8 + kk;
                bf16x8 bh = *(const bf16x8*)Bb;
                bf16x8 bl = *(const bf16x8*)(Bb + 64 * BSTR);
                acc[nt] = __builtin_amdgcn_mfma_f32_32x32x16_bf16(ah, bh, acc[nt], 0, 0, 0);
                acc[nt] = __builtin_amdgcn_mfma_f32_32x32x16_bf16(ah, bl, acc[nt], 0, 0, 0);
                acc[nt] = __builtin_amdgcn_mfma_f32_32x32x16_bf16(al, bh, acc[nt], 0, 0, 0);
            }
        }
    }

    // ---- epilogue: z -> LDS -> LSTM cell update ----
    __syncthreads();
    float* zs = (float*)smem_raw;   // [128][ZSTR]
#pragma unroll
    for (int nt = 0; nt < 2; ++nt)
#pragma unroll
        for (int r = 0; r < 16; ++r) {
            // C/D layout (32x32): col=lane&31, row=(r&3)+8*(r>>2)+4*(lane>>5)
            int rl = w * 32 + (r & 3) + ((r >> 2) << 3) + ((lane >> 5) << 2);
            int col = nt * 32 + l31;
            zs[rl * ZSTR + col] = acc[nt][r];
        }
    __syncthreads();
#pragma unroll
    for (int i = 0; i < 8; ++i) {
        int eid = i * 256 + tid;        // 0..2047 = 128 rows x 16 h-cols
        int hc16 = eid & 15;
        int rl = eid >> 4;
        int rg = row0 + rl;
        int hcol = (cg << 4) + hc16;
        float zi = zs[rl * ZSTR + hc16]      + bias[hcol];
        float zj = zs[rl * ZSTR + 16 + hc16] + bias[512 + hcol];
        float zf = zs[rl * ZSTR + 32 + hc16] + bias[1024 + hcol];
        float zo = zs[rl * ZSTR + 48 + hc16] + bias[1536 + hcol];
        size_t so = (size_t)rg * HDIM + hcol;
        float c_old = c_state[so];
        float h_old = h_state[so];
        int b = rg & 511;
        int sl = (rg >> 9) ? sl2[b] : sl1[b];
        float nc = c_old * sigm(zf + 1.0f) + sigm(zi) * tanh_fast(zj);
        float nh = tanh_fast(nc) * sigm(zo);
        bool valid = t < sl;
        c_state[so] = valid ? nc : c_old;
        h_state[so] = valid ? nh : h_old;
    }
}

// ---------------------------------------------------------------------------
// Head stage 1: build h_combined [512][2056-padded] in global scratch
// grid: 512 blocks (one per batch row), 256 threads
// layout: [h1(512), len1, h2(512), len2, sub(512), lsub, dist, mul(512), lmul]
// ---------------------------------------------------------------------------
__global__ __launch_bounds__(256) void head1(const float* __restrict__ h_state,
                                             const int* __restrict__ sl1,
                                             const int* __restrict__ sl2,
                                             float* __restrict__ hc) {
    int b = blockIdx.x;
    int tid = threadIdx.x;
    const float* h1 = h_state + (size_t)b * HDIM;
    const float* h2 = h_state + (size_t)(512 + b) * HDIM;
    float* row = hc + (size_t)b * 2056;
    float l1 = (float)sl1[b] / (float)TT;
    float l2 = (float)sl2[b] / (float)TT;
    float part = 0.0f;
#pragma unroll
    for (int i = 0; i < 2; ++i) {
        int k = i * 256 + tid;
        float a = h1[k], c = h2[k];
        float s = a - c;
        row[k] = a;
        row[513 + k] = c;
        row[1026 + k] = s;
        row[1540 + k] = a * c;
        part += s * s;
    }
    __shared__ float red[4];
#pragma unroll
    for (int off = 32; off > 0; off >>= 1) part += __shfl_down(part, off, 64);
    if ((tid & 63) == 0) red[tid >> 6] = part;
    __syncthreads();
    if (tid == 0) {
        float d = red[0] + red[1] + red[2] + red[3];
        float ls = l1 - l2;
        d += ls * ls;
        row[512] = l1;
        row[1025] = l2;
        row[1538] = ls;
        row[1539] = d;
        row[2052] = l1 * l2;
    }
}

// ---------------------------------------------------------------------------
// Head stage 2: preds = relu(hc @ W1 + b1) @ W2 + b2
// grid: 64 blocks x 256 threads; each block does 8 batch rows; thread = one W1 col
// ---------------------------------------------------------------------------
__global__ __launch_bounds__(256) void head2(const float* __restrict__ hc,
                                             const float* __restrict__ W1,
                                             const float* __restrict__ b1,
                                             const float* __restrict__ W2,
                                             const float* __restrict__ b2,
                                             float* __restrict__ out) {
    int r8 = blockIdx.x * 8;
    int tid = threadIdx.x;
    float acc[8];
#pragma unroll
    for (int r = 0; r < 8; ++r) acc[r] = 0.0f;
    const float* hcb = hc + (size_t)r8 * 2056;
    for (int k = 0; k < 2053; ++k) {
        float wv = W1[(size_t)k * MDIM + tid];
#pragma unroll
        for (int r = 0; r < 8; ++r) acc[r] += hcb[r * 2056 + k] * wv;
    }
    __shared__ float e1s[8][260];
#pragma unroll
    for (int r = 0; r < 8; ++r) e1s[r][tid] = fmaxf(acc[r] + b1[tid], 0.0f);
    __syncthreads();
    if (tid < 16) {
        int r = tid >> 1, j = tid & 1;
        float s = b2[j];
        for (int c = 0; c < 256; ++c) s += e1s[r][c] * W2[c * 2 + j];
        out[(r8 + r) * 2 + j] = s;
    }
}

// ---------------------------------------------------------------------------
extern "C" void kernel_launch(void* const* d_in, const int* in_sizes, int n_in,
                              void* d_out, int out_size, void* d_ws, size_t ws_size,
                              hipStream_t stream) {
    const int*   in1  = (const int*)d_in[0];
    const int*   in2  = (const int*)d_in[1];
    const int*   sl1  = (const int*)d_in[2];
    const int*   sl2  = (const int*)d_in[3];
    const float* emb  = (const float*)d_in[4];
    const float* kern = (const float*)d_in[5];
    const float* bias = (const float*)d_in[6];
    const float* W1   = (const float*)d_in[7];
    const float* b1   = (const float*)d_in[8];
    const float* W2   = (const float*)d_in[9];
    const float* b2   = (const float*)d_in[10];
    float* out = (float*)d_out;

    char* ws = (char*)d_ws;
    // ws layout (bytes):
    //   c_state  f32 [1024*512]          @ 0         (2 MiB)
    //   h_state  f32 [1024*512]          @ 2 MiB     (2 MiB)
    //   wt_hi    bf16 [2048*832]         @ 4 MiB     (3,407,872)
    //   wt_lo    bf16 [2048*832]                     (3,407,872)
    //   hc       f32 [512*2056]                      (4,210,688)  -> total ~14.6 MiB
    float*  c_state = (float*)ws;
    float*  h_state = (float*)(ws + (1u << 21));
    __bf16* wt_hi   = (__bf16*)(ws + (1u << 22));
    __bf16* wt_lo   = (__bf16*)(ws + (1u << 22) + 3407872u);
    float*  hc      = (float*)(ws + (1u << 22) + 2u * 3407872u);

    // zero c_state + h_state (contiguous 4 MiB)
    hipMemsetAsync(ws, 0, (size_t)1 << 22, stream);

    prep_w<<<dim3(13 * 32), dim3(256), 0, stream>>>(kern, wt_hi, wt_lo);

    for (int t = 0; t < TT; ++t) {
        lstm_step<<<dim3(256), dim3(256), 0, stream>>>(
            t, in1, in2, sl1, sl2, emb, bias, wt_hi, wt_lo, h_state, c_state);
    }

    head1<<<dim3(512), dim3(256), 0, stream>>>(h_state, sl1, sl2, hc);
    head2<<<dim3(64), dim3(256), 0, stream>>>(hc, W1, b1, W2, b2, out);
}

// Round 2
// 1615.393 us; speedup vs baseline: 2.3606x; 2.3606x over previous
//
#include <hip/hip_runtime.h>
#include <hip/hip_bf16.h>

// Problem constants
#define BATCH 512
#define TT 60
#define EDIM 300
#define HDIM 512
#define NG 2048          // 4*H
#define KREAL 812        // E + H
#define KPAD 832         // padded to multiple of 64
#define MDIM 256

typedef __bf16 bf16x4 __attribute__((ext_vector_type(4)));
typedef __bf16 bf16x8 __attribute__((ext_vector_type(8)));
typedef float  f32x16 __attribute__((ext_vector_type(16)));

__device__ __forceinline__ float sigm(float x) {
    return 1.0f / (1.0f + __expf(-x));
}
__device__ __forceinline__ float tanh_fast(float x) {
    float e = __expf(-2.0f * fabsf(x));
    float r = (1.0f - e) / (1.0f + e);
    return x >= 0.0f ? r : -r;
}

// ---------------------------------------------------------------------------
// Weight prep: lstm_kernel [812][2048] fp32 -> Wt_hi/Wt_lo [2048][832] bf16
// (transposed, k-contiguous, zero-padded k in [812,832))
// ---------------------------------------------------------------------------
__global__ __launch_bounds__(256) void prep_w(const float* __restrict__ kern,
                                              __bf16* __restrict__ wt_hi,
                                              __bf16* __restrict__ wt_lo) {
    __shared__ float tile[64][65];
    int bk = blockIdx.x % 13;   // k-tile
    int bn = blockIdx.x / 13;   // n-tile
    int k0 = bk * 64, n0 = bn * 64;
    int tid = threadIdx.x;
#pragma unroll
    for (int i = 0; i < 16; ++i) {
        int id = i * 256 + tid;          // 0..4095
        int kk = id >> 6, nn = id & 63;
        int kg = k0 + kk;
        tile[kk][nn] = (kg < KREAL) ? kern[(size_t)kg * NG + n0 + nn] : 0.0f;
    }
    __syncthreads();
#pragma unroll
    for (int i = 0; i < 2; ++i) {
        int id = i * 256 + tid;          // 0..511
        int nn = id >> 3, k8 = (id & 7) * 8;
        bf16x8 hv, lv;
#pragma unroll
        for (int j = 0; j < 8; ++j) {
            float v = tile[k8 + j][nn];
            __bf16 h = (__bf16)v;
            hv[j] = h;
            lv[j] = (__bf16)(v - (float)h);
        }
        size_t o = (size_t)(n0 + nn) * KPAD + k0 + k8;
        *(bf16x8*)(wt_hi + o) = hv;
        *(bf16x8*)(wt_lo + o) = lv;
    }
}

// ---------------------------------------------------------------------------
// prep_x0: fill X0's embedding part from tokens at t=0 (hi/lo split).
// h-part and pad columns already zeroed by the memset.
// grid 256 x 256 threads; block handles 4 rows.
// ---------------------------------------------------------------------------
__global__ __launch_bounds__(256) void prep_x0(const int* __restrict__ in1,
                                               const int* __restrict__ in2,
                                               const float* __restrict__ emb,
                                               __bf16* __restrict__ Xh,
                                               __bf16* __restrict__ Xl) {
    int row = blockIdx.x * 4 + (threadIdx.x >> 6);
    int lane = threadIdx.x & 63;
    int b = row & 511;
    int tok = ((row >> 9) ? in2 : in1)[b * TT + 0];
    const float* er = emb + (size_t)tok * EDIM;
    __bf16* xh = Xh + (size_t)row * KPAD;
    __bf16* xl = Xl + (size_t)row * KPAD;
#pragma unroll
    for (int i = 0; i < 5; ++i) {
        int c = i * 64 + lane;
        if (c < EDIM) {
            float v = er[c];
            __bf16 h = (__bf16)v;
            xh[c] = h;
            xl[c] = (__bf16)(v - (float)h);
        }
    }
}

// ---------------------------------------------------------------------------
// One LSTM time step for BOTH sequences.
// grid: 256 blocks = 8 batch-tiles (128 rows) x 32 col-groups (16 h-cols).
// block: 512 threads (8 waves = 4 m-strips x 2 k-groups).
// Double-buffered LDS, split-bf16 MFMA 32x32x16, K=832 in 13 chunks of 64.
// A comes pre-split from X (bf16 hi/lo); epilogue writes X for step t+1.
// ---------------------------------------------------------------------------
#define ASTR 72
#define BSTR 72
#define ZSTR 68

__global__ __launch_bounds__(512, 2) void lstm_step(
    int t,
    const int* __restrict__ in1, const int* __restrict__ in2,
    const int* __restrict__ sl1, const int* __restrict__ sl2,
    const float* __restrict__ emb, const float* __restrict__ bias,
    const __bf16* __restrict__ wt_hi, const __bf16* __restrict__ wt_lo,
    const __bf16* __restrict__ Xh, const __bf16* __restrict__ Xl,
    __bf16* __restrict__ Xnh, __bf16* __restrict__ Xnl,
    float* __restrict__ h_state, float* __restrict__ c_state) {

    // LDS: double-buffered A (hi|lo, 128x72 each) and B (hi|lo, 64x72 each)
    __shared__ __align__(16) __bf16 Abuf[2 * 2 * 128 * ASTR];  // 73,728 B
    __shared__ __align__(16) __bf16 Bbuf[2 * 2 * 64 * BSTR];   // 36,864 B
    __shared__ float zs[128 * ZSTR];                           // 34,816 B

    int tid = threadIdx.x;
    int bx = blockIdx.x;
    int bt = bx >> 5;          // batch tile 0..7
    int cg = bx & 31;          // col-group 0..31 (16 h-cols each)
    int row0 = bt * 128;

    int w = tid >> 6;          // wave 0..7
    int lane = tid & 63;
    int l31 = lane & 31;
    int half8 = (lane >> 5) << 3;
    int s = w >> 1;            // m-strip 0..3
    int kg = w & 1;            // k-group 0..1

    // staging register buffers
    bf16x8 rA[4];
    bf16x8 rBv[2];

    // ---- load chunk kc's A/B into registers ----
    auto stage_load = [&](int kc) {
        int k0 = kc * 64;
#pragma unroll
        for (int i = 0; i < 4; ++i) {
            int cid = i * 512 + tid;          // 0..2047
            const __bf16* src = (i >= 2) ? Xl : Xh;
            int r = (cid >> 3) & 127;
            int c8 = (cid & 7) << 3;
            rA[i] = *(const bf16x8*)(src + (size_t)(row0 + r) * KPAD + k0 + c8);
        }
#pragma unroll
        for (int i = 0; i < 2; ++i) {
            const __bf16* srcw = i ? wt_lo : wt_hi;
            int rB = tid >> 3;                // 0..63
            int c8 = (tid & 7) << 3;
            int ng = ((rB >> 4) << 9) + (cg << 4) + (rB & 15);  // gate*512 + cg*16 + c
            rBv[i] = *(const bf16x8*)(srcw + (size_t)ng * KPAD + k0 + c8);
        }
    };
    // ---- store staged registers into LDS buffer `buf` ----
    auto stage_store = [&](int buf) {
        __bf16* Ab = Abuf + buf * (2 * 128 * ASTR);
        __bf16* Bb = Bbuf + buf * (2 * 64 * BSTR);
#pragma unroll
        for (int i = 0; i < 4; ++i) {
            int cid = i * 512 + tid;
            int plane = i >> 1;
            int r = (cid >> 3) & 127;
            int c8 = (cid & 7) << 3;
            *(bf16x8*)(Ab + plane * (128 * ASTR) + r * ASTR + c8) = rA[i];
        }
#pragma unroll
        for (int i = 0; i < 2; ++i) {
            int rB = tid >> 3;
            int c8 = (tid & 7) << 3;
            *(bf16x8*)(Bb + i * (64 * BSTR) + rB * BSTR + c8) = rBv[i];
        }
    };

    f32x16 acc[2];
#pragma unroll
    for (int nt = 0; nt < 2; ++nt)
#pragma unroll
        for (int r = 0; r < 16; ++r) acc[nt][r] = 0.0f;

    stage_load(0);
    stage_store(0);
    __syncthreads();

    for (int kc = 0; kc < 13; ++kc) {
        int cur = kc & 1;
        if (kc < 12) stage_load(kc + 1);   // global loads issue early
        // ---- MFMA on buf cur: wave = m-strip s, k-group kg ----
        const __bf16* Ah = Abuf + cur * (2 * 128 * ASTR) + (s * 32 + l31) * ASTR + kg * 32 + half8;
        const __bf16* Bh = Bbuf + cur * (2 * 64 * BSTR) + l31 * BSTR + kg * 32 + half8;
#pragma unroll
        for (int kk2 = 0; kk2 < 2; ++kk2) {
            int off = kk2 * 16;
            bf16x8 ah = *(const bf16x8*)(Ah + off);
            bf16x8 al = *(const bf16x8*)(Ah + 128 * ASTR + off);
#pragma unroll
            for (int nt = 0; nt < 2; ++nt) {
                const __bf16* Bp = Bh + nt * 32 * BSTR + off;
                bf16x8 bh = *(const bf16x8*)Bp;
                bf16x8 bl = *(const bf16x8*)(Bp + 64 * BSTR);
                acc[nt] = __builtin_amdgcn_mfma_f32_32x32x16_bf16(ah, bh, acc[nt], 0, 0, 0);
                acc[nt] = __builtin_amdgcn_mfma_f32_32x32x16_bf16(ah, bl, acc[nt], 0, 0, 0);
                acc[nt] = __builtin_amdgcn_mfma_f32_32x32x16_bf16(al, bh, acc[nt], 0, 0, 0);
            }
        }
        if (kc < 12) stage_store(1 - cur);
        __syncthreads();
    }

    // ---- combine split-k partials via LDS ----
    if (kg == 0) {
#pragma unroll
        for (int nt = 0; nt < 2; ++nt)
#pragma unroll
            for (int r = 0; r < 16; ++r) {
                int rl = s * 32 + (r & 3) + ((r >> 2) << 3) + ((lane >> 5) << 2);
                int col = nt * 32 + l31;
                zs[rl * ZSTR + col] = acc[nt][r];
            }
    }
    __syncthreads();
    if (kg == 1) {
#pragma unroll
        for (int nt = 0; nt < 2; ++nt)
#pragma unroll
            for (int r = 0; r < 16; ++r) {
                int rl = s * 32 + (r & 3) + ((r >> 2) << 3) + ((lane >> 5) << 2);
                int col = nt * 32 + l31;
                zs[rl * ZSTR + col] += acc[nt][r];
            }
    }
    __syncthreads();

    // ---- LSTM cell update: 128 rows x 16 h-cols = 2048 cells / 512 thr ----
#pragma unroll
    for (int i = 0; i < 4; ++i) {
        int eid = i * 512 + tid;
        int hc16 = eid & 15;
        int rl = eid >> 4;
        int rg = row0 + rl;
        int hcol = (cg << 4) + hc16;
        float zi = zs[rl * ZSTR + hc16]      + bias[hcol];
        float zj = zs[rl * ZSTR + 16 + hc16] + bias[512 + hcol];
        float zf = zs[rl * ZSTR + 32 + hc16] + bias[1024 + hcol];
        float zo = zs[rl * ZSTR + 48 + hc16] + bias[1536 + hcol];
        size_t so = (size_t)rg * HDIM + hcol;
        float c_old = c_state[so];
        float h_old = h_state[so];
        int b = rg & 511;
        int sl = (rg >> 9) ? sl2[b] : sl1[b];
        float nc = c_old * sigm(zf + 1.0f) + sigm(zi) * tanh_fast(zj);
        float nh = tanh_fast(nc) * sigm(zo);
        bool valid = t < sl;
        float cs = valid ? nc : c_old;
        float hs = valid ? nh : h_old;
        c_state[so] = cs;
        h_state[so] = hs;
        // write h-part of next step's X (hi/lo split)
        __bf16 hh = (__bf16)hs;
        Xnh[(size_t)rg * KPAD + EDIM + hcol] = hh;
        Xnl[(size_t)rg * KPAD + EDIM + hcol] = (__bf16)(hs - (float)hh);
    }

    // ---- gather embedding part of next step's X ----
    // cg 0..29 each handle 10 emb cols for this bt's 128 rows
    if (t + 1 < TT && cg < 30) {
        int c0 = cg * 10;
#pragma unroll
        for (int i = 0; i < 3; ++i) {
            int id = i * 512 + tid;          // 0..1279 (128 rows x 10 cols)
            if (id < 1280) {
                int r = id / 10;
                int c = id - r * 10;
                int rg = row0 + r;
                int b = rg & 511;
                int tok = ((rg >> 9) ? in2 : in1)[b * TT + t + 1];
                float v = emb[(size_t)tok * EDIM + c0 + c];
                __bf16 h = (__bf16)v;
                Xnh[(size_t)rg * KPAD + c0 + c] = h;
                Xnl[(size_t)rg * KPAD + c0 + c] = (__bf16)(v - (float)h);
            }
        }
    }
}

// ---------------------------------------------------------------------------
// Head stage 1: build h_combined [512][2056-padded] in global scratch
// ---------------------------------------------------------------------------
__global__ __launch_bounds__(256) void head1(const float* __restrict__ h_state,
                                             const int* __restrict__ sl1,
                                             const int* __restrict__ sl2,
                                             float* __restrict__ hc) {
    int b = blockIdx.x;
    int tid = threadIdx.x;
    const float* h1 = h_state + (size_t)b * HDIM;
    const float* h2 = h_state + (size_t)(512 + b) * HDIM;
    float* row = hc + (size_t)b * 2056;
    float l1 = (float)sl1[b] / (float)TT;
    float l2 = (float)sl2[b] / (float)TT;
    float part = 0.0f;
#pragma unroll
    for (int i = 0; i < 2; ++i) {
        int k = i * 256 + tid;
        float a = h1[k], c = h2[k];
        float s = a - c;
        row[k] = a;
        row[513 + k] = c;
        row[1026 + k] = s;
        row[1540 + k] = a * c;
        part += s * s;
    }
    __shared__ float red[4];
#pragma unroll
    for (int off = 32; off > 0; off >>= 1) part += __shfl_down(part, off, 64);
    if ((tid & 63) == 0) red[tid >> 6] = part;
    __syncthreads();
    if (tid == 0) {
        float d = red[0] + red[1] + red[2] + red[3];
        float ls = l1 - l2;
        d += ls * ls;
        row[512] = l1;
        row[1025] = l2;
        row[1538] = ls;
        row[1539] = d;
        row[2052] = l1 * l2;
        row[2053] = 0.0f;
        row[2054] = 0.0f;
        row[2055] = 0.0f;
    }
}

// ---------------------------------------------------------------------------
// Head stage 2: preds = relu(hc @ W1 + b1) @ W2 + b2
// 256 blocks x 256 threads; block = 2 batch rows; thread = one W1 column.
// hc rows staged in LDS (broadcast reads), W1 streamed coalesced.
// ---------------------------------------------------------------------------
__global__ __launch_bounds__(256) void head2(const float* __restrict__ hc,
                                             const float* __restrict__ W1,
                                             const float* __restrict__ b1,
                                             const float* __restrict__ W2,
                                             const float* __restrict__ b2,
                                             float* __restrict__ out) {
    int r2 = blockIdx.x * 2;
    int tid = threadIdx.x;
    __shared__ float4 hs[2][514];
    __shared__ float e1s[2][260];
    const float4* r0 = (const float4*)(hc + (size_t)r2 * 2056);
    const float4* r1 = (const float4*)(hc + (size_t)(r2 + 1) * 2056);
    for (int i = tid; i < 514; i += 256) {
        hs[0][i] = r0[i];
        hs[1][i] = r1[i];
    }
    __syncthreads();
    float a0 = 0.0f, a1 = 0.0f;
    for (int k4 = 0; k4 < 513; ++k4) {
        float4 h0 = hs[0][k4];
        float4 h1 = hs[1][k4];
        int kb = k4 * 4;
        float w0 = W1[(size_t)(kb + 0) * MDIM + tid];
        float w1 = W1[(size_t)(kb + 1) * MDIM + tid];
        float w2 = W1[(size_t)(kb + 2) * MDIM + tid];
        float w3 = W1[(size_t)(kb + 3) * MDIM + tid];
        a0 += h0.x * w0 + h0.y * w1 + h0.z * w2 + h0.w * w3;
        a1 += h1.x * w0 + h1.y * w1 + h1.z * w2 + h1.w * w3;
    }
    {   // tail k = 2052
        float wl = W1[(size_t)2052 * MDIM + tid];
        a0 += ((const float*)&hs[0][513])[0] * wl;
        a1 += ((const float*)&hs[1][513])[0] * wl;
    }
    e1s[0][tid] = fmaxf(a0 + b1[tid], 0.0f);
    e1s[1][tid] = fmaxf(a1 + b1[tid], 0.0f);
    __syncthreads();
    if (tid < 4) {
        int r = tid >> 1, j = tid & 1;
        float sacc = b2[j];
        for (int c = 0; c < 256; ++c) sacc += e1s[r][c] * W2[c * 2 + j];
        out[(r2 + r) * 2 + j] = sacc;
    }
}

// ---------------------------------------------------------------------------
extern "C" void kernel_launch(void* const* d_in, const int* in_sizes, int n_in,
                              void* d_out, int out_size, void* d_ws, size_t ws_size,
                              hipStream_t stream) {
    const int*   in1  = (const int*)d_in[0];
    const int*   in2  = (const int*)d_in[1];
    const int*   sl1  = (const int*)d_in[2];
    const int*   sl2  = (const int*)d_in[3];
    const float* emb  = (const float*)d_in[4];
    const float* kern = (const float*)d_in[5];
    const float* bias = (const float*)d_in[6];
    const float* W1   = (const float*)d_in[7];
    const float* b1   = (const float*)d_in[8];
    const float* W2   = (const float*)d_in[9];
    const float* b2   = (const float*)d_in[10];
    float* out = (float*)d_out;

    char* ws = (char*)d_ws;
    // ws layout (bytes):
    //   c_state f32 [1024*512]   @ 0            (2,097,152)
    //   h_state f32 [1024*512]   @ 2,097,152    (2,097,152)
    //   X0h bf16 [1024*832]      @ 4,194,304    (1,703,936)
    //   X0l                      @ 5,898,240
    //   X1h                      @ 7,602,176
    //   X1l                      @ 9,306,112    -> 11,010,048
    //   wt_hi bf16 [2048*832]    @ 11,010,048   (3,407,872)
    //   wt_lo                    @ 14,417,920
    //   hc f32 [512*2056]        @ 17,825,792   (4,210,688) -> 22,036,480 total
    float*  c_state = (float*)ws;
    float*  h_state = (float*)(ws + 2097152u);
    __bf16* X0h = (__bf16*)(ws + 4194304u);
    __bf16* X0l = (__bf16*)(ws + 5898240u);
    __bf16* X1h = (__bf16*)(ws + 7602176u);
    __bf16* X1l = (__bf16*)(ws + 9306112u);
    __bf16* wt_hi = (__bf16*)(ws + 11010048u);
    __bf16* wt_lo = (__bf16*)(ws + 14417920u);
    float*  hc = (float*)(ws + 17825792u);

    // zero c_state, h_state, X0, X1 in one shot
    hipMemsetAsync(ws, 0, 11010048u, stream);

    prep_w<<<dim3(13 * 32), dim3(256), 0, stream>>>(kern, wt_hi, wt_lo);
    prep_x0<<<dim3(256), dim3(256), 0, stream>>>(in1, in2, emb, X0h, X0l);

    for (int t = 0; t < TT; ++t) {
        __bf16* Xh  = (t & 1) ? X1h : X0h;
        __bf16* Xl  = (t & 1) ? X1l : X0l;
        __bf16* Xnh = (t & 1) ? X0h : X1h;
        __bf16* Xnl = (t & 1) ? X0l : X1l;
        lstm_step<<<dim3(256), dim3(512), 0, stream>>>(
            t, in1, in2, sl1, sl2, emb, bias, wt_hi, wt_lo,
            Xh, Xl, Xnh, Xnl, h_state, c_state);
    }

    head1<<<dim3(512), dim3(256), 0, stream>>>(h_state, sl1, sl2, hc);
    head2<<<dim3(256), dim3(256), 0, stream>>>(hc, W1, b1, W2, b2, out);
}